// Round 9
// baseline (180.758 us; speedup 1.0000x reference)
//
#include <hip/hip_runtime.h>
#include <hip/hip_bf16.h>
#include <stdint.h>

// Problem constants (B=1)
#define NN   256     // MSA depth (contraction K of GEMM1)
#define LL   192
#define MDIM 6144    // L*J
#define D2   1024    // J*J
#define FF   128     // n_feat_out

typedef __bf16 bf16x8 __attribute__((ext_vector_type(8)));
typedef float  f32x4  __attribute__((ext_vector_type(4)));

#define MFMA16(a, b, c) __builtin_amdgcn_mfma_f32_16x16x32_bf16(a, b, c, 0, 0, 0)

static __device__ __forceinline__ unsigned short bf16_bits(float v) {
  __bf16 h = (__bf16)v;
  return __builtin_bit_cast(unsigned short, h);
}

// ---------------------------------------------------------------------------
// Unified prep (one launch):
//  blocks [0,1536):    transpose x_down  [256][6144] f32 -> At [6144][256] bf16
//  blocks [1536,3072): transpose x_down_w            -> Bt
//  blocks [3072,3200): WB[fragment-linear] = bf16(a2*W), S = colsum, T = b2@W+b
// ---------------------------------------------------------------------------
__global__ __launch_bounds__(256)
void prep_all(const float* __restrict__ x1, const float* __restrict__ x2,
              const float* __restrict__ W, const float* __restrict__ a2,
              const float* __restrict__ b2, const float* __restrict__ bias,
              __bf16* __restrict__ At, __bf16* __restrict__ Bt,
              __bf16* __restrict__ WB, float* __restrict__ S,
              float* __restrict__ T) {
  __shared__ float tile[32][33];
  const int b = blockIdx.x;
  const int t = threadIdx.x;
  if (b < 3072) {
    const float* src = (b < 1536) ? x1 : x2;
    __bf16* dst = (b < 1536) ? At : Bt;
    const int bb = (b < 1536) ? b : b - 1536;
    const int m0 = (bb % 192) * 32;
    const int k0 = (bb / 192) * 32;
    {
      const int kr = t >> 3, mc = (t & 7) * 4;
      const float4 v = *(const float4*)&src[(size_t)(k0 + kr) * MDIM + m0 + mc];
      tile[kr][mc + 0] = v.x;
      tile[kr][mc + 1] = v.y;
      tile[kr][mc + 2] = v.z;
      tile[kr][mc + 3] = v.w;
    }
    __syncthreads();
    {
      const int mr = t >> 3, kc = (t & 7) * 4;
      ushort4 u;
      u.x = bf16_bits(tile[kc + 0][mr]);
      u.y = bf16_bits(tile[kc + 1][mr]);
      u.z = bf16_bits(tile[kc + 2][mr]);
      u.w = bf16_bits(tile[kc + 3][mr]);
      *(ushort4*)&dst[(size_t)(m0 + mr) * NN + k0 + kc] = u;
    }
  } else {
    const int f = b - 3072;
    float s = 0.f, tt = 0.f;
#pragma unroll
    for (int it = 0; it < 4; ++it) {
      const int k = t + it * 256;
      const float wv = W[(size_t)k * FF + f];
      const __bf16 wa = (__bf16)(a2[k] * wv);
      WB[(size_t)(k >> 5) * 4096 + f * 32 + ((k >> 3) & 3) * 8 + (k & 7)] = wa;
      s += (float)wa;
      tt += b2[k] * wv;
    }
#pragma unroll
    for (int off = 32; off; off >>= 1) {
      s += __shfl_xor(s, off);
      tt += __shfl_xor(tt, off);
    }
    const int wv_ = t >> 6, ln = t & 63;
    if (ln == 0) { tile[0][wv_] = s; tile[1][wv_] = tt; }
    __syncthreads();
    if (t == 0) {
      S[f] = tile[0][0] + tile[0][1] + tile[0][2] + tile[0][3];
      T[f] = tile[1][0] + tile[1][1] + tile[1][2] + tile[1][3] + bias[f];
    }
  }
}

// ---------------------------------------------------------------------------
// Fused kernel R9: direct-global GEMM1 (no LDS staging, ZERO barriers in the
// K-loop) + XCD banding (b&7 = XCD, 12x24 rectangle -> band L2-resident) +
// spill-free (256,4). Waves are fully decoupled until the single Xs barrier.
// Fragment loads hit the ~2.6MB band in L2 (~200cyc); waves 0/2 share A rows
// and 0/1 share B rows so L1 absorbs ~half. Phase register discipline (R7):
//   GEMM1: acc 64(AGPR) + a/b frags 32 + addr ~16   (arch side < 64)
//   scatter: acc(dying) + WB depth-2 prefetch 16
//   GEMM2: acc2 8 + WB depth-8 pipe 64 (acc dead; pinned by sched_barrier)
// Spill tripwire: WRITE_SIZE must be exactly 18432 KB.
// out = rstd*(x@Wa - mean*S) + T
// ---------------------------------------------------------------------------
__global__ __launch_bounds__(256, 4)
void fused9(const __bf16* __restrict__ At, const __bf16* __restrict__ Bt,
            const __bf16* __restrict__ WB, const float* __restrict__ S,
            const float* __restrict__ T, float* __restrict__ out) {
  __shared__ uint8_t lds[32768];      // Xs[16][1024] bf16 (swizzled) only
  __shared__ float mean_s[16], rstd_s[16];

  const int tid = threadIdx.x;
  const int w = tid >> 6;            // wave 0..3
  const int lane = tid & 63;
  const int q = lane >> 4;           // quad
  const int c = lane & 15;

  // ---- XCD banding: b&7 = XCD (round-robin dispatch), 12x24 rectangle ----
  const int b = blockIdx.x;
  const int xcd = b & 7;
  const int s_ = b >> 3;             // 0..287
  const int bx = (xcd >> 1) * 12 + (s_ % 12);
  const int by = (xcd & 1) * 24 + (s_ / 12);
  const int m0 = bx * 128, n0 = by * 128;

  const int mbase = (w & 1) * 64;
  const int nbase = (w >> 1) * 64;

  f32x4 acc[4][4];
#pragma unroll
  for (int i = 0; i < 4; ++i)
#pragma unroll
    for (int j = 0; j < 4; ++j)
      acc[i][j] = (f32x4){0.f, 0.f, 0.f, 0.f};

  // ---------------- GEMM1: 8 k-steps of 32, direct from global, no barriers --
  {
    const __bf16* pa = At + (size_t)(m0 + mbase + c) * NN + q * 8;
    const __bf16* pb = Bt + (size_t)(n0 + nbase + c) * NN + q * 8;
#pragma unroll 1
    for (int ks = 0; ks < 8; ++ks) {
      bf16x8 a[4], bfr[4];
#pragma unroll
      for (int t4 = 0; t4 < 4; ++t4) {
        a[t4]   = *(const bf16x8*)(pa + (size_t)t4 * 16 * NN);
        bfr[t4] = *(const bf16x8*)(pb + (size_t)t4 * 16 * NN);
      }
#pragma unroll
      for (int ti = 0; ti < 4; ++ti)
#pragma unroll
        for (int tj = 0; tj < 4; ++tj)
          acc[ti][tj] = MFMA16(a[ti], bfr[tj], acc[ti][tj]);
      pa += 32;
      pb += 32;
    }
  }

  // ------------- GEMM2 depth-2 prefetch (held shallow while acc is live) -----
  const int fb = w * 32;
  const __bf16* wb0 = WB + (fb + c) * 32 + q * 8;
  const __bf16* wb1 = WB + (fb + 16 + c) * 32 + q * 8;
  bf16x8 pb0[8], pb1[8];
  pb0[0] = *(const bf16x8*)(wb0);
  pb0[1] = *(const bf16x8*)(wb0 + 4096);
  pb1[0] = *(const bf16x8*)(wb1);
  pb1[1] = *(const bf16x8*)(wb1 + 4096);

  // ------------- LN stats (in-wave) + packed-b32 swizzled scatter -------------
  // No barrier needed before this: LDS (Xs region) has no prior use.
  // Xs byte addr for element (row r, k): g=k>>3; G = g ^ (g>>4) ^ (r&7);
  // addr = r*2048 + G*16 + (k&7)*2
  const int i_hi = w & 1, l_hi = w >> 1;
#pragma unroll
  for (int ab = 0; ab < 2; ++ab) {
#pragma unroll
    for (int cb = 0; cb < 2; ++cb) {
      float s1 = 0.f, s2 = 0.f;
#pragma unroll
      for (int dti = 0; dti < 2; ++dti)
#pragma unroll
        for (int dtj = 0; dtj < 2; ++dtj)
#pragma unroll
          for (int reg = 0; reg < 4; ++reg) {
            const float v = acc[ab * 2 + dti][cb * 2 + dtj][reg];
            s1 += v; s2 += v * v;
          }
#pragma unroll
      for (int off = 32; off; off >>= 1) {
        s1 += __shfl_xor(s1, off);
        s2 += __shfl_xor(s2, off);
      }
      const float mean = s1 * (1.0f / 1024.0f);
      const float var = s2 * (1.0f / 1024.0f) - mean * mean;
      const float rstd = rsqrtf(var + 1e-5f);
      const int r = (i_hi * 2 + ab) * 4 + (l_hi * 2 + cb);
      if (lane == 0) { mean_s[r] = mean; rstd_s[r] = rstd; }
      const int r7 = r & 7;
#pragma unroll
      for (int dti = 0; dti < 2; ++dti)
#pragma unroll
        for (int dtj = 0; dtj < 2; ++dtj)
#pragma unroll
          for (int rp = 0; rp < 4; rp += 2) {
            const float x = acc[ab * 2 + dti][cb * 2 + dtj][rp];
            const float y = acc[ab * 2 + dti][cb * 2 + dtj][rp + 1];
            const float send = (c & 1) ? x : y;
            const float recv = __shfl_xor(send, 1);
            const float vlo = (c & 1) ? recv : x;
            const float vhi = (c & 1) ? y : recv;
            const int reg_w = (c & 1) ? rp + 1 : rp;
            const int j = dti * 16 + q * 4 + reg_w;
            const int mm0 = dtj * 16 + (c & ~1);
            const int k = j * 32 + mm0;
            const int g = k >> 3;
            const int G = g ^ (g >> 4) ^ r7;
            const uint32_t dw =
                ((uint32_t)bf16_bits(vhi) << 16) | (uint32_t)bf16_bits(vlo);
            *(uint32_t*)(lds + r * 2048 + G * 16 + (mm0 & 7) * 2) = dw;
          }
    }
  }

  __syncthreads();   // THE single barrier: Xs + stats visible; acc DEAD below
  __builtin_amdgcn_sched_barrier(0);   // pin the deepening loads BELOW here

  // ------------- deepen WB pipeline to 8 pairs (acc registers freed) -------------
#pragma unroll
  for (int p = 2; p < 8; ++p) {
    pb0[p] = *(const bf16x8*)(wb0 + p * 4096);
    pb1[p] = *(const bf16x8*)(wb1 + p * 4096);
  }

  // ------------- GEMM2: Xs(16x1024) @ Wa^T -> 16x128, depth-8 pipeline -------------
  f32x4 acc2[2];
  acc2[0] = (f32x4){0.f, 0.f, 0.f, 0.f};
  acc2[1] = (f32x4){0.f, 0.f, 0.f, 0.f};
  const int c7 = c & 7;
#pragma unroll
  for (int kstep = 0; kstep < 32; ++kstep) {
    const int g = kstep * 4 + q;
    const int G = g ^ (g >> 4) ^ c7;
    const bf16x8 av = *(const bf16x8*)(lds + c * 2048 + G * 16);
    acc2[0] = MFMA16(av, pb0[kstep & 7], acc2[0]);
    acc2[1] = MFMA16(av, pb1[kstep & 7], acc2[1]);
    if (kstep < 24) {
      pb0[kstep & 7] = *(const bf16x8*)(wb0 + (kstep + 8) * 4096);
      pb1[kstep & 7] = *(const bf16x8*)(wb1 + (kstep + 8) * 4096);
    }
  }

  // ------------- epilogue: affine + store (S/T loaded only now) -------------
  const float S0 = S[fb + c], T0 = T[fb + c];
  const float S1 = S[fb + 16 + c], T1 = T[fb + 16 + c];
#pragma unroll
  for (int reg = 0; reg < 4; ++reg) {
    const int r = q * 4 + reg;             // LN row 0..15
    const float mean = mean_s[r], rstd = rstd_s[r];
    const int i = bx * 4 + (r >> 2);
    const int l = by * 4 + (r & 3);
    const size_t base = ((size_t)i * LL + l) * FF;
    out[base + fb + c]      = rstd * (acc2[0][reg] - mean * S0) + T0;
    out[base + fb + 16 + c] = rstd * (acc2[1][reg] - mean * S1) + T1;
  }
}

// ---------------------------------------------------------------------------
extern "C" void kernel_launch(void* const* d_in, const int* in_sizes, int n_in,
                              void* d_out, int out_size, void* d_ws, size_t ws_size,
                              hipStream_t stream) {
  const float* x_down   = (const float*)d_in[0];
  const float* x_down_w = (const float*)d_in[1];
  const float* a2       = (const float*)d_in[2];
  const float* b2       = (const float*)d_in[3];
  const float* W        = (const float*)d_in[4];
  const float* bias     = (const float*)d_in[5];
  float* out = (float*)d_out;

  uint8_t* ws = (uint8_t*)d_ws;
  __bf16* At  = (__bf16*)(ws);                 // 6144*256*2 = 3145728 B
  __bf16* Bt  = (__bf16*)(ws + 3145728);       // 3145728 B
  __bf16* WB  = (__bf16*)(ws + 6291456);       // 128*1024*2 = 262144 B
  float*  S   = (float*)(ws + 6553600);        // 512 B
  float*  T   = (float*)(ws + 6554112);        // 512 B

  prep_all<<<dim3(3200), dim3(256), 0, stream>>>(x_down, x_down_w, W, a2, b2,
                                                 bias, At, Bt, WB, S, T);
  fused9<<<dim3(2304), dim3(256), 0, stream>>>(At, Bt, WB, S, T, out);
}

// Round 10
// 126.387 us; speedup vs baseline: 1.4302x; 1.4302x over previous
//
#include <hip/hip_runtime.h>
#include <hip/hip_bf16.h>
#include <stdint.h>

// Problem constants (B=1)
#define NN   256     // MSA depth (contraction K of GEMM1)
#define LL   192
#define MDIM 6144    // L*J
#define D2   1024    // J*J
#define FF   128     // n_feat_out

typedef __bf16 bf16x8 __attribute__((ext_vector_type(8)));
typedef float  f32x4  __attribute__((ext_vector_type(4)));

#define MFMA16(a, b, c) __builtin_amdgcn_mfma_f32_16x16x32_bf16(a, b, c, 0, 0, 0)

__device__ __forceinline__ void gload_lds16(const void* g, void* l) {
  __builtin_amdgcn_global_load_lds(
      (__attribute__((address_space(1))) void*)(g),
      (__attribute__((address_space(3))) void*)(l),
      16, 0, 0);
}

static __device__ __forceinline__ unsigned short bf16_bits(float v) {
  __bf16 h = (__bf16)v;
  return __builtin_bit_cast(unsigned short, h);
}

// ---------------------------------------------------------------------------
// Unified prep (one launch):
//  blocks [0,1536):    transpose x_down  [256][6144] f32 -> At [6144][256] bf16
//  blocks [1536,3072): transpose x_down_w            -> Bt
//  blocks [3072,3200): WB[fragment-linear] = bf16(a2*W), S = colsum, T = b2@W+b
// ---------------------------------------------------------------------------
__global__ __launch_bounds__(256)
void prep_all(const float* __restrict__ x1, const float* __restrict__ x2,
              const float* __restrict__ W, const float* __restrict__ a2,
              const float* __restrict__ b2, const float* __restrict__ bias,
              __bf16* __restrict__ At, __bf16* __restrict__ Bt,
              __bf16* __restrict__ WB, float* __restrict__ S,
              float* __restrict__ T) {
  __shared__ float tile[32][33];
  const int b = blockIdx.x;
  const int t = threadIdx.x;
  if (b < 3072) {
    const float* src = (b < 1536) ? x1 : x2;
    __bf16* dst = (b < 1536) ? At : Bt;
    const int bb = (b < 1536) ? b : b - 1536;
    const int m0 = (bb % 192) * 32;
    const int k0 = (bb / 192) * 32;
    {
      const int kr = t >> 3, mc = (t & 7) * 4;
      const float4 v = *(const float4*)&src[(size_t)(k0 + kr) * MDIM + m0 + mc];
      tile[kr][mc + 0] = v.x;
      tile[kr][mc + 1] = v.y;
      tile[kr][mc + 2] = v.z;
      tile[kr][mc + 3] = v.w;
    }
    __syncthreads();
    {
      const int mr = t >> 3, kc = (t & 7) * 4;
      ushort4 u;
      u.x = bf16_bits(tile[kc + 0][mr]);
      u.y = bf16_bits(tile[kc + 1][mr]);
      u.z = bf16_bits(tile[kc + 2][mr]);
      u.w = bf16_bits(tile[kc + 3][mr]);
      *(ushort4*)&dst[(size_t)(m0 + mr) * NN + k0 + kc] = u;
    }
  } else {
    const int f = b - 3072;
    float s = 0.f, tt = 0.f;
#pragma unroll
    for (int it = 0; it < 4; ++it) {
      const int k = t + it * 256;
      const float wv = W[(size_t)k * FF + f];
      const __bf16 wa = (__bf16)(a2[k] * wv);
      WB[(size_t)(k >> 5) * 4096 + f * 32 + ((k >> 3) & 3) * 8 + (k & 7)] = wa;
      s += (float)wa;
      tt += b2[k] * wv;
    }
#pragma unroll
    for (int off = 32; off; off >>= 1) {
      s += __shfl_xor(s, off);
      tt += __shfl_xor(tt, off);
    }
    const int wv_ = t >> 6, ln = t & 63;
    if (ln == 0) { tile[0][wv_] = s; tile[1][wv_] = tt; }
    __syncthreads();
    if (t == 0) {
      S[f] = tile[0][0] + tile[0][1] + tile[0][2] + tile[0][3];
      T[f] = tile[1][0] + tile[1][1] + tile[1][2] + tile[1][3] + bias[f];
    }
  }
}

// ---------------------------------------------------------------------------
// Fused kernel R10: 128x256 tile / 512 threads (8 waves). Per-wave structure
// identical to the proven R8 (64x64 GEMM1 slice, BK=64 global_load_lds
// staging, 128B-row XOR swizzle). Rationale: fused time tracks L2-read bytes
// at ~14 TB/s across R1/R3/R8; the dominant term is the per-block 256KB WB
// re-read. Doubling the tile's LN rows (16->32) halves WB bytes per output:
// L2 reads 900MB -> ~516MB total.
//   - 2 blocks/CU (LDS 64KB: staging 48KB aliased in Xs 64KB), 16 waves/CU.
//   - __launch_bounds__(512,4): same 128-reg/thread budget R8 proved
//     spill-free; R8 phase discipline (WB depth-2 while acc lives, depth-8
//     after sched_barrier). Spill tripwire: WRITE_SIZE == 18432 KB exactly.
//   - GEMM2: wave w owns f-slice w*16 (16 cols), 32 LN rows via two A-frags
//     per kstep sharing one WB B-frag.
//   - Banding: 1152 blocks = 8 XCDs x (12x12) rectangles, band ~2.6MB.
// out = rstd*(x@Wa - mean*S) + T
// ---------------------------------------------------------------------------
__global__ __launch_bounds__(512, 4)
void fused10(const __bf16* __restrict__ At, const __bf16* __restrict__ Bt,
             const __bf16* __restrict__ WB, const float* __restrict__ S,
             const float* __restrict__ T, float* __restrict__ out) {
  __shared__ uint8_t lds[65536];      // staging (A 16K @0, B 32K @16K) / Xs[32][2048]
  __shared__ float mean_s[32], rstd_s[32];

  const int tid = threadIdx.x;
  const int w = tid >> 6;            // wave 0..7
  const int lane = tid & 63;
  const int q = lane >> 4;           // quad
  const int c = lane & 15;

  // ---- XCD banding: b&7 = XCD (round-robin dispatch), 12x12 rectangle ----
  const int b = blockIdx.x;
  const int xcd = b & 7;
  const int s_ = b >> 3;             // 0..143
  const int bx = (xcd >> 1) * 12 + (s_ % 12);   // 0..47  (m, 128-wide)
  const int by = (xcd & 1) * 12 + (s_ / 12);    // 0..23  (n, 256-wide)
  const int m0 = bx * 128, n0 = by * 256;

  uint8_t* As = lds;                 // 128 rows x 128B
  uint8_t* Bs = lds + 16384;         // 256 rows x 128B

  // staging lane decomposition: 8 lanes per 128B row (BK=64 bf16)
  const int l8 = lane & 7;
  const int r8 = lane >> 3;
  const int gsw = l8 ^ r8;           // XOR-swizzled source 16B-group

  f32x4 acc[4][4];
#pragma unroll
  for (int i = 0; i < 4; ++i)
#pragma unroll
    for (int j = 0; j < 4; ++j)
      acc[i][j] = (f32x4){0.f, 0.f, 0.f, 0.f};

  const int mbase = (w & 1) * 64;    // wave grid 2(m) x 4(n)
  const int nbase = (w >> 1) * 64;

  // ---------------- GEMM1 K-loop: 4 chunks of BK=64 (rolled) ----------------
  {
    const __bf16* gA = At + (size_t)(m0 + w * 16 + r8) * NN + gsw * 8;
    const __bf16* gB = Bt + (size_t)(n0 + w * 32 + r8) * NN + gsw * 8;
#pragma unroll 1
    for (int kb = 0; kb < 4; ++kb) {
      __syncthreads();
      // A: 16 rows/wave (2 instr), B: 32 rows/wave (4 instr)
#pragma unroll
      for (int j = 0; j < 2; ++j)
        gload_lds16(gA + (size_t)j * 8 * NN, As + (w * 16 + j * 8) * 128);
#pragma unroll
      for (int j = 0; j < 4; ++j)
        gload_lds16(gB + (size_t)j * 8 * NN, Bs + (w * 32 + j * 8) * 128);
      __syncthreads();
#pragma unroll
      for (int ks = 0; ks < 2; ++ks) {
        const int slot = ((ks * 4 + q) ^ (lane & 7)) * 16;
        bf16x8 a[4];
#pragma unroll
        for (int t4 = 0; t4 < 4; ++t4)
          a[t4] = *(const bf16x8*)(As + (mbase + t4 * 16 + c) * 128 + slot);
#pragma unroll
        for (int tj = 0; tj < 4; ++tj) {
          const bf16x8 bfr =
              *(const bf16x8*)(Bs + (nbase + tj * 16 + c) * 128 + slot);
#pragma unroll
          for (int ti = 0; ti < 4; ++ti)
            acc[ti][tj] = MFMA16(a[ti], bfr, acc[ti][tj]);
        }
      }
      gA += 64;
      gB += 64;
    }
  }

  // ------------- GEMM2 depth-2 prefetch (held shallow while acc is live) -----
  const int fs = w * 16;             // this wave's 16-f slice
  const __bf16* wbp = WB + (fs + c) * 32 + q * 8;   // + kstep*4096 elements
  bf16x8 pb[8];
  pb[0] = *(const bf16x8*)(wbp);
  pb[1] = *(const bf16x8*)(wbp + 4096);

  __syncthreads();   // all staging ds_reads done; lds becomes Xs[32][2048]

  // ------------- LN stats (in-wave) + packed-b32 swizzled scatter -------------
  // Xs byte addr for element (row r, k): g=k>>3; G = g ^ (g>>4) ^ (r&7);
  // addr = r*2048 + G*16 + (k&7)*2
  const int i_hi = w & 1, l_hi = w >> 1;   // i_local = i_hi*2+ab, l_local = l_hi*2+cb
#pragma unroll
  for (int ab = 0; ab < 2; ++ab) {
#pragma unroll
    for (int cb = 0; cb < 2; ++cb) {
      float s1 = 0.f, s2 = 0.f;
#pragma unroll
      for (int dti = 0; dti < 2; ++dti)
#pragma unroll
        for (int dtj = 0; dtj < 2; ++dtj)
#pragma unroll
          for (int reg = 0; reg < 4; ++reg) {
            const float v = acc[ab * 2 + dti][cb * 2 + dtj][reg];
            s1 += v; s2 += v * v;
          }
#pragma unroll
      for (int off = 32; off; off >>= 1) {
        s1 += __shfl_xor(s1, off);
        s2 += __shfl_xor(s2, off);
      }
      const float mean = s1 * (1.0f / 1024.0f);
      const float var = s2 * (1.0f / 1024.0f) - mean * mean;
      const float rstd = rsqrtf(var + 1e-5f);
      const int r = (i_hi * 2 + ab) * 8 + l_hi * 2 + cb;   // 0..31
      if (lane == 0) { mean_s[r] = mean; rstd_s[r] = rstd; }
      const int r7 = r & 7;
#pragma unroll
      for (int dti = 0; dti < 2; ++dti)
#pragma unroll
        for (int dtj = 0; dtj < 2; ++dtj)
#pragma unroll
          for (int rp = 0; rp < 4; rp += 2) {
            const float x = acc[ab * 2 + dti][cb * 2 + dtj][rp];
            const float y = acc[ab * 2 + dti][cb * 2 + dtj][rp + 1];
            const float send = (c & 1) ? x : y;
            const float recv = __shfl_xor(send, 1);
            const float vlo = (c & 1) ? recv : x;
            const float vhi = (c & 1) ? y : recv;
            const int reg_w = (c & 1) ? rp + 1 : rp;
            const int j = dti * 16 + q * 4 + reg_w;
            const int mm0 = dtj * 16 + (c & ~1);
            const int k = j * 32 + mm0;
            const int g = k >> 3;
            const int G = g ^ (g >> 4) ^ r7;
            const uint32_t dw =
                ((uint32_t)bf16_bits(vhi) << 16) | (uint32_t)bf16_bits(vlo);
            *(uint32_t*)(lds + r * 2048 + G * 16 + (mm0 & 7) * 2) = dw;
          }
    }
  }

  __syncthreads();   // Xs + stats visible; acc DEAD below
  __builtin_amdgcn_sched_barrier(0);   // pin the deepening loads BELOW here

  // ------------- deepen WB pipeline to 8 (acc registers freed) -------------
#pragma unroll
  for (int p = 2; p < 8; ++p)
    pb[p] = *(const bf16x8*)(wbp + p * 4096);

  // ------------- GEMM2: Xs(32x1024) @ Wa^T -> 32x16 (per wave), depth-8 ------
  f32x4 acc2[2];
  acc2[0] = (f32x4){0.f, 0.f, 0.f, 0.f};
  acc2[1] = (f32x4){0.f, 0.f, 0.f, 0.f};
  const int c7 = c & 7;
#pragma unroll
  for (int kstep = 0; kstep < 32; ++kstep) {
    const int g = kstep * 4 + q;
    const int G = g ^ (g >> 4) ^ c7;
    const bf16x8 a0 = *(const bf16x8*)(lds + c * 2048 + G * 16);
    const bf16x8 a1 = *(const bf16x8*)(lds + (16 + c) * 2048 + G * 16);
    acc2[0] = MFMA16(a0, pb[kstep & 7], acc2[0]);
    acc2[1] = MFMA16(a1, pb[kstep & 7], acc2[1]);
    if (kstep < 24)
      pb[kstep & 7] = *(const bf16x8*)(wbp + (kstep + 8) * 4096);
  }

  // ------------- epilogue: affine + store (S/T loaded only now) -------------
  const float S0 = S[fs + c], T0 = T[fs + c];
#pragma unroll
  for (int reg = 0; reg < 4; ++reg) {
    const int r0 = q * 4 + reg;            // LN rows 0..15 (acc2[0])
    const int r1 = 16 + r0;                // LN rows 16..31 (acc2[1])
    {
      const float mean = mean_s[r0], rstd = rstd_s[r0];
      const int i = bx * 4 + (r0 >> 3);
      const int l = by * 8 + (r0 & 7);
      out[((size_t)i * LL + l) * FF + fs + c] =
          rstd * (acc2[0][reg] - mean * S0) + T0;
    }
    {
      const float mean = mean_s[r1], rstd = rstd_s[r1];
      const int i = bx * 4 + (r1 >> 3);
      const int l = by * 8 + (r1 & 7);
      out[((size_t)i * LL + l) * FF + fs + c] =
          rstd * (acc2[1][reg] - mean * S0) + T0;
    }
  }
}

// ---------------------------------------------------------------------------
extern "C" void kernel_launch(void* const* d_in, const int* in_sizes, int n_in,
                              void* d_out, int out_size, void* d_ws, size_t ws_size,
                              hipStream_t stream) {
  const float* x_down   = (const float*)d_in[0];
  const float* x_down_w = (const float*)d_in[1];
  const float* a2       = (const float*)d_in[2];
  const float* b2       = (const float*)d_in[3];
  const float* W        = (const float*)d_in[4];
  const float* bias     = (const float*)d_in[5];
  float* out = (float*)d_out;

  uint8_t* ws = (uint8_t*)d_ws;
  __bf16* At  = (__bf16*)(ws);                 // 6144*256*2 = 3145728 B
  __bf16* Bt  = (__bf16*)(ws + 3145728);       // 3145728 B
  __bf16* WB  = (__bf16*)(ws + 6291456);       // 128*1024*2 = 262144 B
  float*  S   = (float*)(ws + 6553600);        // 512 B
  float*  T   = (float*)(ws + 6554112);        // 512 B

  prep_all<<<dim3(3200), dim3(256), 0, stream>>>(x_down, x_down_w, W, a2, b2,
                                                 bias, At, Bt, WB, S, T);
  fused10<<<dim3(1152), dim3(512), 0, stream>>>(At, Bt, WB, S, T, out);
}